// Round 13
// baseline (350.708 us; speedup 1.0000x reference)
//
#include <hip/hip_runtime.h>
#include <hip/hip_bf16.h>
#include <math.h>

// Sizes fixed by the reference: B=128 T=128 N=16 D=128 H=128 C=4096
#define BT   16384
#define CC   4096

typedef __attribute__((ext_vector_type(8))) short short8v;     // 8 bf16 (4 VGPRs)
typedef __attribute__((ext_vector_type(8))) unsigned short ushort8v;
typedef __attribute__((ext_vector_type(4))) float f32x4;
typedef __attribute__((ext_vector_type(2))) _Float16 h2v;

// RNE float -> bf16 bits
__device__ __forceinline__ unsigned short f2bf(float f) {
  union { float f; unsigned int u; } v; v.f = f;
  unsigned int r = (v.u + 0x7fffu + ((v.u >> 16) & 1u)) >> 16;
  return (unsigned short)r;
}

// fast sigmoid / tanh via native exp (inf-safe at both extremes)
__device__ __forceinline__ float fsig(float x) {
  return 1.0f / (1.0f + __expf(-x));
}
__device__ __forceinline__ float ftanh(float x) {
  return 1.0f - 2.0f / (__expf(2.0f * x) + 1.0f);
}

// f16 pair dot with f32 accumulate; hbits carries 2 f16 in a float's bits.
__device__ __forceinline__ float dot2f(float hbits, unsigned int ubits,
                                       float acc) {
#if __has_builtin(__builtin_amdgcn_fdot2)
  h2v ha = __builtin_bit_cast(h2v, hbits);
  h2v ub = __builtin_bit_cast(h2v, ubits);
  return __builtin_amdgcn_fdot2(ha, ub, acc, false);
#else
  union { unsigned int u; _Float16 h[2]; } A, B;
  A.u = __builtin_bit_cast(unsigned int, hbits);
  B.u = ubits;
  return acc + (float)A.h[0] * (float)B.h[0] + (float)A.h[1] * (float)B.h[1];
#endif
}

// ---------------------------------------------------------------------------
// prep_dots (round-2 exact): builds bf16
//   wqT[c=g*128+d][k] = sum_m w_g[k][m]*ak_g[m][d]        (ak top half)
//   wcT[g][n<128][k]  = w_g[k][n]
//   wcT[g][128+d][k]  = sum_m w_g[k][m]*ak_g[128+m][d]    (ak bottom half)
//   abp[c] (f32)      = ab_g[d]
// ---------------------------------------------------------------------------
__global__ __launch_bounds__(128) void prep_dots_kernel(
    const float* __restrict__ s_w, const float* __restrict__ s_ak,
    const float* __restrict__ s_ab, const float* __restrict__ t_w,
    const float* __restrict__ t_ak, const float* __restrict__ t_ab,
    unsigned short* __restrict__ wqT, unsigned short* __restrict__ wcT,
    float* __restrict__ abp) {
  int d = blockIdx.x, quad = blockIdx.y;
  int g = quad & 1;
  const float* w  = g ? t_w  : s_w;
  const float* ak = g ? t_ak : s_ak;
  int akoff = (quad >> 1) ? 128 : 0;
  __shared__ float akcol[128];
  int k = threadIdx.x;
  akcol[k] = ak[(akoff + k) * 128 + d];
  if (quad < 2) {
    wcT[g * 32768 + d * 128 + k] = f2bf(w[k * 128 + d]);
    if (k == 0) abp[g * 128 + d] = g ? t_ab[d] : s_ab[d];
  }
  __syncthreads();
  float acc = 0.f;
  #pragma unroll 8
  for (int m = 0; m < 128; ++m) acc = fmaf(w[k * 128 + m], akcol[m], acc);
  if (quad < 2) wqT[(g * 128 + d) * 128 + k] = f2bf(acc);
  else          wcT[g * 32768 + (128 + d) * 128 + k] = f2bf(acc);
}

// ---------------------------------------------------------------------------
// Wf[128][4096] -> WfT[4096][128] bf16 (round-2 exact). grid (128,4), 256 thr
// ---------------------------------------------------------------------------
__global__ __launch_bounds__(256) void prep_wfT_kernel(
    const float* __restrict__ Wf, unsigned short* __restrict__ WfT) {
  __shared__ float tile[32][33];
  int n0 = blockIdx.x * 32, k0 = blockIdx.y * 32;
  int c = threadIdx.x & 31, r0 = threadIdx.x >> 5;
  #pragma unroll
  for (int i = 0; i < 4; ++i) {
    int r = r0 + i * 8;
    tile[r][c] = Wf[(size_t)(k0 + r) * 4096 + n0 + c];
  }
  __syncthreads();
  #pragma unroll
  for (int i = 0; i < 4; ++i) {
    int r = r0 + i * 8;  // n index
    WfT[(size_t)(n0 + r) * 128 + k0 + c] = f2bf(tile[c][r]);
  }
}

// ---------------------------------------------------------------------------
// Transpose+convert: src f32 [128][N] -> dst bf16 [N][128]. grid (N/32,4,z)
// ---------------------------------------------------------------------------
__global__ __launch_bounds__(256) void tconv_kernel(
    const float* __restrict__ s0, const float* __restrict__ s1,
    const float* __restrict__ s2, unsigned short* __restrict__ d0,
    unsigned short* __restrict__ d1, unsigned short* __restrict__ d2, int N) {
  int z = blockIdx.z;
  const float* src = (z == 0) ? s0 : (z == 1) ? s1 : s2;
  unsigned short* dst = (z == 0) ? d0 : (z == 1) ? d1 : d2;
  __shared__ float tile[32][33];
  int n0 = blockIdx.x * 32, k0 = blockIdx.y * 32;
  int c = threadIdx.x & 31, r0 = threadIdx.x >> 5;
  #pragma unroll
  for (int i = 0; i < 4; ++i) {
    int r = r0 + i * 8;
    tile[r][c] = src[(size_t)(k0 + r) * N + n0 + c];
  }
  __syncthreads();
  #pragma unroll
  for (int i = 0; i < 4; ++i) {
    int r = r0 + i * 8;  // n index
    dst[(size_t)(n0 + r) * 128 + k0 + c] = f2bf(tile[c][r]);
  }
}

// ---------------------------------------------------------------------------
// Uh f32 [128][512] -> packed f16-pair table UhH[k2][j] = (Uh[2k2][j],
// Uh[2k2+1][j]) as one uint. grid 128 x 256 (32768 entries).
// ---------------------------------------------------------------------------
__global__ __launch_bounds__(256) void uhconv_kernel(
    const float* __restrict__ Uh, unsigned int* __restrict__ UhH) {
  int idx = blockIdx.x * 256 + threadIdx.x;  // k2*512 + j
  int k2 = idx >> 9, j = idx & 511;
  float a = Uh[(size_t)(2 * k2) * 512 + j];
  float b = Uh[(size_t)(2 * k2 + 1) * 512 + j];
  union { _Float16 h[2]; unsigned int u; } p;
  p.h[0] = (_Float16)a;
  p.h[1] = (_Float16)b;
  UhH[idx] = p.u;
}

// ---------------------------------------------------------------------------
// x fp32 -> bf16, 8 elems/thread (round-2 exact). grid 1024 x 256
// ---------------------------------------------------------------------------
__global__ __launch_bounds__(256) void xconv_kernel(
    const float* __restrict__ x, unsigned short* __restrict__ xb) {
  int i = blockIdx.x * 256 + threadIdx.x;
  const float4* x4 = (const float4*)x;
  float4 a = x4[(size_t)i * 2], b = x4[(size_t)i * 2 + 1];
  ushort8v v;
  v[0] = f2bf(a.x); v[1] = f2bf(a.y); v[2] = f2bf(a.z); v[3] = f2bf(a.w);
  v[4] = f2bf(b.x); v[5] = f2bf(b.y); v[6] = f2bf(b.z); v[7] = f2bf(b.w);
  *(ushort8v*)(xb + (size_t)i * 8) = v;
}

// ---------------------------------------------------------------------------
// MFMA GEMM (round-2 exact, single A/B): C[M][N] = A[M][128]@BT[N][128]^T+bias
// Block tile 128x64, 256 thr = 4 waves. XOR-swizzle (row&7)<<4 on 16B chunks.
// ---------------------------------------------------------------------------
__global__ __launch_bounds__(256) void mfma_gemm_kernel(
    const unsigned short* __restrict__ A, const unsigned short* __restrict__ BTm,
    const float* __restrict__ bias, float* __restrict__ C, int N) {
  __shared__ unsigned short As[128 * 128];
  __shared__ unsigned short Bs[64 * 128];
  int tid = threadIdx.x;
  int m0 = blockIdx.x * 128, n0 = blockIdx.y * 64;
  #pragma unroll
  for (int i = 0; i < 8; ++i) {
    int cix = i * 256 + tid, row = cix >> 4, ch = cix & 15;
    ushort8v v = *(const ushort8v*)(A + (size_t)(m0 + row) * 128 + ch * 8);
    *(ushort8v*)&As[row * 128 + ((ch ^ (row & 7)) << 3)] = v;
  }
  #pragma unroll
  for (int i = 0; i < 4; ++i) {
    int cix = i * 256 + tid, row = cix >> 4, ch = cix & 15;
    ushort8v v = *(const ushort8v*)(BTm + (size_t)(n0 + row) * 128 + ch * 8);
    *(ushort8v*)&Bs[row * 128 + ((ch ^ (row & 7)) << 3)] = v;
  }
  __syncthreads();
  int lane = tid & 63, w = tid >> 6;
  int col = lane & 15, grp = lane >> 4;

  f32x4 acc[2][4];
  #pragma unroll
  for (int tm = 0; tm < 2; ++tm)
    #pragma unroll
    for (int tn = 0; tn < 4; ++tn) acc[tm][tn] = (f32x4){0.f, 0.f, 0.f, 0.f};

  #pragma unroll
  for (int kk = 0; kk < 4; ++kk) {
    int ch = kk * 4 + grp;
    short8v af[2], bf[4];
    #pragma unroll
    for (int tm = 0; tm < 2; ++tm) {
      int row = w * 32 + tm * 16 + col;
      af[tm] = *(const short8v*)&As[row * 128 + ((ch ^ (row & 7)) << 3)];
    }
    #pragma unroll
    for (int tn = 0; tn < 4; ++tn) {
      int row = tn * 16 + col;
      bf[tn] = *(const short8v*)&Bs[row * 128 + ((ch ^ (row & 7)) << 3)];
    }
    #pragma unroll
    for (int tm = 0; tm < 2; ++tm)
      #pragma unroll
      for (int tn = 0; tn < 4; ++tn)
        acc[tm][tn] = __builtin_amdgcn_mfma_f32_16x16x32_bf16(af[tm], bf[tn],
                                                              acc[tm][tn], 0, 0, 0);
  }

  #pragma unroll
  for (int tm = 0; tm < 2; ++tm)
    #pragma unroll
    for (int tn = 0; tn < 4; ++tn) {
      int cg = n0 + tn * 16 + col;
      float bv = bias[cg];
      int rbase = m0 + w * 32 + tm * 16 + grp * 4;
      #pragma unroll
      for (int r = 0; r < 4; ++r)
        C[(size_t)(rbase + r) * N + cg] = acc[tm][tn][r] + bv;
    }
}

// ---------------------------------------------------------------------------
// Multi-mat MFMA GEMM (round-4 exact): C = sum_s A_s@BT_s^T + bias.
// ---------------------------------------------------------------------------
__global__ __launch_bounds__(256) void mfma_gemm3_kernel(
    const unsigned short* __restrict__ A0, const unsigned short* __restrict__ A1,
    const unsigned short* __restrict__ A2, const unsigned short* __restrict__ B0,
    const unsigned short* __restrict__ B1, const unsigned short* __restrict__ B2,
    int nmat, const float* __restrict__ bias, float* __restrict__ C, int N) {
  __shared__ unsigned short As[128 * 128];
  __shared__ unsigned short Bs[64 * 128];
  int tid = threadIdx.x;
  int m0 = blockIdx.x * 128, n0 = blockIdx.y * 64;
  int lane = tid & 63, w = tid >> 6;
  int col = lane & 15, grp = lane >> 4;

  f32x4 acc[2][4];
  #pragma unroll
  for (int tm = 0; tm < 2; ++tm)
    #pragma unroll
    for (int tn = 0; tn < 4; ++tn) acc[tm][tn] = (f32x4){0.f, 0.f, 0.f, 0.f};

  for (int s = 0; s < nmat; ++s) {
    const unsigned short* A   = (s == 0) ? A0 : (s == 1) ? A1 : A2;
    const unsigned short* BTm = (s == 0) ? B0 : (s == 1) ? B1 : B2;
    if (s) __syncthreads();
    #pragma unroll
    for (int i = 0; i < 8; ++i) {
      int cix = i * 256 + tid, row = cix >> 4, ch = cix & 15;
      ushort8v v = *(const ushort8v*)(A + (size_t)(m0 + row) * 128 + ch * 8);
      *(ushort8v*)&As[row * 128 + ((ch ^ (row & 7)) << 3)] = v;
    }
    #pragma unroll
    for (int i = 0; i < 4; ++i) {
      int cix = i * 256 + tid, row = cix >> 4, ch = cix & 15;
      ushort8v v = *(const ushort8v*)(BTm + (size_t)(n0 + row) * 128 + ch * 8);
      *(ushort8v*)&Bs[row * 128 + ((ch ^ (row & 7)) << 3)] = v;
    }
    __syncthreads();

    #pragma unroll
    for (int kk = 0; kk < 4; ++kk) {
      int ch = kk * 4 + grp;
      short8v af[2], bf[4];
      #pragma unroll
      for (int tm = 0; tm < 2; ++tm) {
        int row = w * 32 + tm * 16 + col;
        af[tm] = *(const short8v*)&As[row * 128 + ((ch ^ (row & 7)) << 3)];
      }
      #pragma unroll
      for (int tn = 0; tn < 4; ++tn) {
        int row = tn * 16 + col;
        bf[tn] = *(const short8v*)&Bs[row * 128 + ((ch ^ (row & 7)) << 3)];
      }
      #pragma unroll
      for (int tm = 0; tm < 2; ++tm)
        #pragma unroll
        for (int tn = 0; tn < 4; ++tn)
          acc[tm][tn] = __builtin_amdgcn_mfma_f32_16x16x32_bf16(
              af[tm], bf[tn], acc[tm][tn], 0, 0, 0);
    }
  }

  #pragma unroll
  for (int tm = 0; tm < 2; ++tm)
    #pragma unroll
    for (int tn = 0; tn < 4; ++tn) {
      int cg = n0 + tn * 16 + col;
      float bv = bias[cg];
      int rbase = m0 + w * 32 + tm * 16 + grp * 4;
      #pragma unroll
      for (int r = 0; r < 4; ++r)
        C[(size_t)(rbase + r) * N + cg] = acc[tm][tn][r] + bv;
    }
}

// ---------------------------------------------------------------------------
// GAT via MFMA v6: bt-PAIR processing with shared B-fragment reads.
// grid (512, 2), 256 thr = 4 waves; wave owns 8 bt = 4 pairs.
// Per pair: each B-frag ds_read_b128 feeds TWO MFMAs (bt0, bt1) -> B reads
// halve to 32/bt (LDS pipe was the binding floor at 64/bt). Register fit via
// column-half split: softmax group t only needs tiles (t, 8+t), so process
// nt in two halves -> acc = 2bt x 8 tiles = 64 VGPRs (same as round-8).
// Prefetch: raw f32 A of the NEXT pair issued before the MFMA block,
// converted to bf16 af[] AFTER the softmax (full pair-step covers latency).
// ---------------------------------------------------------------------------
__global__ __launch_bounds__(256) void gat_mfma_kernel(
    const float* __restrict__ sneigh, const float* __restrict__ tneigh,
    const unsigned short* __restrict__ wcT, const float* __restrict__ qb,
    unsigned short* __restrict__ spb, unsigned short* __restrict__ tpb) {
  int g = blockIdx.y;
  const float* neigh = g ? tneigh : sneigh;
  const unsigned short* wc = wcT + g * 32768;
  unsigned short* outp = g ? tpb : spb;

  __shared__ unsigned short Bsh[256 * 128];  // 64 KB, swizzled
  int tid = threadIdx.x;
  #pragma unroll
  for (int i = 0; i < 16; ++i) {
    int cix = i * 256 + tid, row = cix >> 4, ch = cix & 15;
    ushort8v v = *(const ushort8v*)(wc + row * 128 + ch * 8);
    *(ushort8v*)&Bsh[row * 128 + ((ch ^ (row & 7)) << 3)] = v;
  }
  __syncthreads();

  int lane = tid & 63, wid = tid >> 6;
  int col = lane & 15, grp = lane >> 4;

  int btbase = blockIdx.x * 32 + wid * 8;  // 8 bt per wave (4 pairs)

  float4 raw[16];      // prefetch buffer: raw f32 A of a pair
  short8v af[2][4];    // current pair's bf16 A fragments

  auto load_pair = [&](int bt) {
    const float* nb = neigh + ((size_t)bt * 16 + col) * 128 + grp * 8;
    #pragma unroll
    for (int kk = 0; kk < 4; ++kk) {
      raw[2 * kk]     = *(const float4*)(nb + kk * 32);
      raw[2 * kk + 1] = *(const float4*)(nb + kk * 32 + 4);
    }
    const float* nb1 = nb + 2048;  // +16 rows = bt+1
    #pragma unroll
    for (int kk = 0; kk < 4; ++kk) {
      raw[8 + 2 * kk]     = *(const float4*)(nb1 + kk * 32);
      raw[8 + 2 * kk + 1] = *(const float4*)(nb1 + kk * 32 + 4);
    }
  };

  auto cvt_pair = [&]() {
    #pragma unroll
    for (int bb = 0; bb < 2; ++bb)
      #pragma unroll
      for (int kk = 0; kk < 4; ++kk) {
        float4 a = raw[bb * 8 + 2 * kk], b = raw[bb * 8 + 2 * kk + 1];
        short8v t;
        t[0] = (short)f2bf(a.x); t[1] = (short)f2bf(a.y);
        t[2] = (short)f2bf(a.z); t[3] = (short)f2bf(a.w);
        t[4] = (short)f2bf(b.x); t[5] = (short)f2bf(b.y);
        t[6] = (short)f2bf(b.z); t[7] = (short)f2bf(b.w);
        af[bb][kk] = t;
      }
  };

  load_pair(btbase);
  cvt_pair();

  for (int p = 0; p < 4; ++p) {
    int bt = btbase + 2 * p;
    int btn = (p < 3) ? bt + 2 : bt;  // clamped, always-valid prefetch

    // q loads for the current pair (latency covered by half-0 MFMAs)
    float qv[2][8];
    {
      const float* qrow = qb + (size_t)bt * 256 + g * 128 + col;
      #pragma unroll
      for (int t = 0; t < 8; ++t) {
        qv[0][t] = qrow[t * 16];
        qv[1][t] = qrow[256 + t * 16];
      }
    }

    load_pair(btn);  // prefetch next pair's raw A (af holds current pair)

    #pragma unroll
    for (int hf = 0; hf < 2; ++hf) {
      f32x4 acc[2][8];  // [bt-in-pair][j: 0-3 pn cols, 4-7 r cols]
      #pragma unroll
      for (int bb = 0; bb < 2; ++bb)
        #pragma unroll
        for (int j = 0; j < 8; ++j) acc[bb][j] = (f32x4){0.f, 0.f, 0.f, 0.f};

      #pragma unroll
      for (int kk = 0; kk < 4; ++kk) {
        int ch = kk * 4 + grp;
        #pragma unroll
        for (int j = 0; j < 8; ++j) {
          int nt = (j < 4) ? (hf * 4 + j) : (4 + hf * 4 + j);  // r: 8+hf*4+(j-4)
          int row = nt * 16 + col;
          short8v bfv =
              *(const short8v*)&Bsh[row * 128 + ((ch ^ (row & 7)) << 3)];
          acc[0][j] = __builtin_amdgcn_mfma_f32_16x16x32_bf16(af[0][kk], bfv,
                                                              acc[0][j], 0, 0, 0);
          acc[1][j] = __builtin_amdgcn_mfma_f32_16x16x32_bf16(af[1][kk], bfv,
                                                              acc[1][j], 0, 0, 0);
        }
      }

      // softmax over n + weighted sum for t in this half; d = 16*t + col
      #pragma unroll
      for (int bb = 0; bb < 2; ++bb) {
        #pragma unroll
        for (int tj = 0; tj < 4; ++tj) {
          int t = hf * 4 + tj;
          float qvv = qv[bb][t];
          float e0 = qvv + acc[bb][4 + tj][0], e1 = qvv + acc[bb][4 + tj][1];
          float e2 = qvv + acc[bb][4 + tj][2], e3 = qvv + acc[bb][4 + tj][3];
          e0 = (e0 > 0.f) ? e0 : 0.2f * e0;
          e1 = (e1 > 0.f) ? e1 : 0.2f * e1;
          e2 = (e2 > 0.f) ? e2 : 0.2f * e2;
          e3 = (e3 > 0.f) ? e3 : 0.2f * e3;
          float mx = fmaxf(fmaxf(e0, e1), fmaxf(e2, e3));
          mx = fmaxf(mx, __shfl_xor(mx, 16));
          mx = fmaxf(mx, __shfl_xor(mx, 32));
          float p0 = __expf(e0 - mx), p1 = __expf(e1 - mx);
          float p2 = __expf(e2 - mx), p3 = __expf(e3 - mx);
          float s = p0 + p1 + p2 + p3;
          float o = p0 * acc[bb][tj][0] + p1 * acc[bb][tj][1] +
                    p2 * acc[bb][tj][2] + p3 * acc[bb][tj][3];
          s += __shfl_xor(s, 16); s += __shfl_xor(s, 32);
          o += __shfl_xor(o, 16); o += __shfl_xor(o, 32);
          if (grp == (t & 3))
            outp[(size_t)(bt + bb) * 128 + t * 16 + col] = f2bf(o / s);
        }
      }
    }

    cvt_pair();  // waits on prefetch loads; prepares af for the next pair
  }
}

// ---------------------------------------------------------------------------
// LSTM scan v6 (round-11 exact, best measured): 512 thr, lb(512,2), f16-pair
// dot2 matvec; h f16 in LDS; Uh packed f16 pairs in 64 VGPRs.
// ---------------------------------------------------------------------------
__global__ __launch_bounds__(512, 2) void lstm_kernel(
    const float* __restrict__ pre, const unsigned int* __restrict__ UhH,
    unsigned short* __restrict__ hsb) {
  int b = blockIdx.x;
  int j = threadIdx.x;
  __shared__ _Float16 hh[128];
  __shared__ float nl_lds[512];
  unsigned int u2[64];
  #pragma unroll
  for (int k2 = 0; k2 < 64; ++k2) u2[k2] = UhH[k2 * 512 + j];
  float c = 0.f;
  if (j < 128) hh[j] = (_Float16)0.f;
  __syncthreads();
  const float4* hv4 = (const float4*)hh;  // 16 float4 = 128 f16
  const float* prow = pre + (size_t)b * 128 * 512 + j;
  unsigned short* hrow = hsb + (size_t)b * 128 * 128 + (j & 127);
  float pcur = prow[0];
  for (int t = 0; t < 128; ++t) {
    float pnext = (t < 127) ? prow[(size_t)(t + 1) * 512] : 0.f;

    // g = pcur + h @ Uh[:,j] via f16 dot2, 4 independent chains
    float ga = pcur, gb = 0.f, gc = 0.f, gd = 0.f;
    #pragma unroll
    for (int i = 0; i < 4; ++i) {
      float4 v0 = hv4[i * 4 + 0];
      float4 v1 = hv4[i * 4 + 1];
      float4 v2 = hv4[i * 4 + 2];
      float4 v3 = hv4[i * 4 + 3];
      int kb = i * 16;
      ga = dot2f(v0.x, u2[kb + 0], ga);
      gb = dot2f(v0.y, u2[kb + 1], gb);
      gc = dot2f(v0.z, u2[kb + 2], gc);
      gd = dot2f(v0.w, u2[kb + 3], gd);
      ga = dot2f(v1.x, u2[kb + 4], ga);
      gb = dot2f(v1.y, u2[kb + 5], gb);
      gc = dot2f(v1.z, u2[kb + 6], gc);
      gd = dot2f(v1.w, u2[kb + 7], gd);
      ga = dot2f(v2.x, u2[kb + 8], ga);
      gb = dot2f(v2.y, u2[kb + 9], gb);
      gc = dot2f(v2.z, u2[kb + 10], gc);
      gd = dot2f(v2.w, u2[kb + 11], gd);
      ga = dot2f(v3.x, u2[kb + 12], ga);
      gb = dot2f(v3.y, u2[kb + 13], gb);
      gc = dot2f(v3.z, u2[kb + 14], gc);
      gd = dot2f(v3.w, u2[kb + 15], gd);
    }
    float g = (ga + gb) + (gc + gd);

    // nonlinearity on ALL threads (wave-uniform branch: j<384 <=> wave<6)
    float nl = (j < 384) ? fsig(g) : ftanh(g);
    nl_lds[j] = nl;
    __syncthreads();  // partials ready; hh reads of this step done

    if (j < 128) {
      float ig = nl_lds[j], fg = nl_lds[j + 128];
      float og = nl_lds[j + 256], cg = nl_lds[j + 384];
      c = fg * c + ig * cg;
      float h = ftanh(og * c);
      hh[j] = (_Float16)h;
      hrow[(size_t)t * 128] = f2bf(h);
    }
    __syncthreads();
    pcur = pnext;
  }
}

// ---------------------------------------------------------------------------
extern "C" void kernel_launch(void* const* d_in, const int* in_sizes, int n_in,
                              void* d_out, int out_size, void* d_ws,
                              size_t ws_size, hipStream_t stream) {
  const float* x    = (const float*)d_in[0];
  const float* sn   = (const float*)d_in[1];
  const float* tn   = (const float*)d_in[2];
  const float* s_w  = (const float*)d_in[3];
  const float* s_ak = (const float*)d_in[4];
  const float* s_ab = (const float*)d_in[5];
  const float* t_w  = (const float*)d_in[6];
  const float* t_ak = (const float*)d_in[7];
  const float* t_ab = (const float*)d_in[8];
  const float* Wx   = (const float*)d_in[9];
  const float* Uh   = (const float*)d_in[10];
  const float* Ub   = (const float*)d_in[11];
  const float* sW   = (const float*)d_in[12];
  const float* tW   = (const float*)d_in[13];
  const float* Wf   = (const float*)d_in[14];
  const float* bfb  = (const float*)d_in[15];
  float* out = (float*)d_out;

  // ws layout — byte-identical to rounds 2/4/5/6/8/11 (proven to fit):
  unsigned short* wqT = (unsigned short*)d_ws;                      // 65536 B
  unsigned short* wcT = (unsigned short*)((char*)d_ws + 65536);     // 131072 B
  unsigned short* WfT = (unsigned short*)((char*)d_ws + 196608);    // 1048576 B
  unsigned short* hsb = (unsigned short*)((char*)d_ws + 1245184);   // 4194304 B
  float*          abp = (float*)((char*)d_ws + 5439488);            // 1024 B

  // d_out scratch — byte-identical to round 11:
  float* pre = out;                                        // [0, 8388608)
  float* q   = out + 12582912;                             // [16384][256]
  unsigned short* xb  = (unsigned short*)(out + 16777216); // [16384][128] bf16
  unsigned short* spb = (unsigned short*)(out + 17825792); // [16384][128] bf16
  unsigned short* tpb = (unsigned short*)(out + 18874368); // [16384][128] bf16
  unsigned short* WxT = (unsigned short*)(out + 19922944); // [512][128] bf16
  unsigned short* sWT = (unsigned short*)(out + 19955712); // [512][128] bf16
  unsigned short* tWT = (unsigned short*)(out + 19988480); // [512][128] bf16
  unsigned int*   UhH = (unsigned int*)(out + 20054016);   // [64][512] uint

  prep_dots_kernel<<<dim3(128, 4), 128, 0, stream>>>(s_w, s_ak, s_ab, t_w, t_ak,
                                                     t_ab, wqT, wcT, abp);
  prep_wfT_kernel<<<dim3(128, 4), 256, 0, stream>>>(Wf, WfT);
  tconv_kernel<<<dim3(16, 4, 3), 256, 0, stream>>>(Wx, sW, tW, WxT, sWT, tWT,
                                                   512);
  uhconv_kernel<<<128, 256, 0, stream>>>(Uh, UhH);
  xconv_kernel<<<1024, 256, 0, stream>>>(x, xb);
  mfma_gemm_kernel<<<dim3(128, 4), 256, 0, stream>>>(xb, wqT, abp, q, 256);
  gat_mfma_kernel<<<dim3(512, 2), 256, 0, stream>>>(sn, tn, wcT, q, spb, tpb);
  mfma_gemm3_kernel<<<dim3(128, 8), 256, 0, stream>>>(xb, spb, tpb, WxT, sWT,
                                                      tWT, 3, Ub, pre, 512);
  lstm_kernel<<<128, 512, 0, stream>>>(pre, UhH, hsb);
  mfma_gemm_kernel<<<dim3(128, 64), 256, 0, stream>>>(hsb, WfT, bfb, out, CC);
}

// Round 14
// 293.835 us; speedup vs baseline: 1.1936x; 1.1936x over previous
//
#include <hip/hip_runtime.h>
#include <hip/hip_bf16.h>
#include <math.h>

// Sizes fixed by the reference: B=128 T=128 N=16 D=128 H=128 C=4096
#define BT   16384
#define CC   4096

typedef __attribute__((ext_vector_type(8))) short short8v;     // 8 bf16 (4 VGPRs)
typedef __attribute__((ext_vector_type(8))) unsigned short ushort8v;
typedef __attribute__((ext_vector_type(4))) float f32x4;
typedef __attribute__((ext_vector_type(2))) _Float16 h2v;

// RNE float -> bf16 bits
__device__ __forceinline__ unsigned short f2bf(float f) {
  union { float f; unsigned int u; } v; v.f = f;
  unsigned int r = (v.u + 0x7fffu + ((v.u >> 16) & 1u)) >> 16;
  return (unsigned short)r;
}

// fast sigmoid / tanh via native exp (inf-safe at both extremes)
__device__ __forceinline__ float fsig(float x) {
  return 1.0f / (1.0f + __expf(-x));
}
__device__ __forceinline__ float ftanh(float x) {
  return 1.0f - 2.0f / (__expf(2.0f * x) + 1.0f);
}

// f16 pair dot with f32 accumulate; hbits carries 2 f16 in a float's bits.
__device__ __forceinline__ float dot2f(float hbits, unsigned int ubits,
                                       float acc) {
#if __has_builtin(__builtin_amdgcn_fdot2)
  h2v ha = __builtin_bit_cast(h2v, hbits);
  h2v ub = __builtin_bit_cast(h2v, ubits);
  return __builtin_amdgcn_fdot2(ha, ub, acc, false);
#else
  union { unsigned int u; _Float16 h[2]; } A, B;
  A.u = __builtin_bit_cast(unsigned int, hbits);
  B.u = ubits;
  return acc + (float)A.h[0] * (float)B.h[0] + (float)A.h[1] * (float)B.h[1];
#endif
}

// ---------------------------------------------------------------------------
// prep_dots (round-2 exact): builds bf16
//   wqT[c=g*128+d][k] = sum_m w_g[k][m]*ak_g[m][d]        (ak top half)
//   wcT[g][n<128][k]  = w_g[k][n]
//   wcT[g][128+d][k]  = sum_m w_g[k][m]*ak_g[128+m][d]    (ak bottom half)
//   abp[c] (f32)      = ab_g[d]
// ---------------------------------------------------------------------------
__global__ __launch_bounds__(128) void prep_dots_kernel(
    const float* __restrict__ s_w, const float* __restrict__ s_ak,
    const float* __restrict__ s_ab, const float* __restrict__ t_w,
    const float* __restrict__ t_ak, const float* __restrict__ t_ab,
    unsigned short* __restrict__ wqT, unsigned short* __restrict__ wcT,
    float* __restrict__ abp) {
  int d = blockIdx.x, quad = blockIdx.y;
  int g = quad & 1;
  const float* w  = g ? t_w  : s_w;
  const float* ak = g ? t_ak : s_ak;
  int akoff = (quad >> 1) ? 128 : 0;
  __shared__ float akcol[128];
  int k = threadIdx.x;
  akcol[k] = ak[(akoff + k) * 128 + d];
  if (quad < 2) {
    wcT[g * 32768 + d * 128 + k] = f2bf(w[k * 128 + d]);
    if (k == 0) abp[g * 128 + d] = g ? t_ab[d] : s_ab[d];
  }
  __syncthreads();
  float acc = 0.f;
  #pragma unroll 8
  for (int m = 0; m < 128; ++m) acc = fmaf(w[k * 128 + m], akcol[m], acc);
  if (quad < 2) wqT[(g * 128 + d) * 128 + k] = f2bf(acc);
  else          wcT[g * 32768 + (128 + d) * 128 + k] = f2bf(acc);
}

// ---------------------------------------------------------------------------
// Wf[128][4096] -> WfT[4096][128] bf16 (round-2 exact). grid (128,4), 256 thr
// ---------------------------------------------------------------------------
__global__ __launch_bounds__(256) void prep_wfT_kernel(
    const float* __restrict__ Wf, unsigned short* __restrict__ WfT) {
  __shared__ float tile[32][33];
  int n0 = blockIdx.x * 32, k0 = blockIdx.y * 32;
  int c = threadIdx.x & 31, r0 = threadIdx.x >> 5;
  #pragma unroll
  for (int i = 0; i < 4; ++i) {
    int r = r0 + i * 8;
    tile[r][c] = Wf[(size_t)(k0 + r) * 4096 + n0 + c];
  }
  __syncthreads();
  #pragma unroll
  for (int i = 0; i < 4; ++i) {
    int r = r0 + i * 8;  // n index
    WfT[(size_t)(n0 + r) * 128 + k0 + c] = f2bf(tile[c][r]);
  }
}

// ---------------------------------------------------------------------------
// Transpose+convert: src f32 [128][N] -> dst bf16 [N][128]. grid (N/32,4,z)
// ---------------------------------------------------------------------------
__global__ __launch_bounds__(256) void tconv_kernel(
    const float* __restrict__ s0, const float* __restrict__ s1,
    const float* __restrict__ s2, unsigned short* __restrict__ d0,
    unsigned short* __restrict__ d1, unsigned short* __restrict__ d2, int N) {
  int z = blockIdx.z;
  const float* src = (z == 0) ? s0 : (z == 1) ? s1 : s2;
  unsigned short* dst = (z == 0) ? d0 : (z == 1) ? d1 : d2;
  __shared__ float tile[32][33];
  int n0 = blockIdx.x * 32, k0 = blockIdx.y * 32;
  int c = threadIdx.x & 31, r0 = threadIdx.x >> 5;
  #pragma unroll
  for (int i = 0; i < 4; ++i) {
    int r = r0 + i * 8;
    tile[r][c] = src[(size_t)(k0 + r) * N + n0 + c];
  }
  __syncthreads();
  #pragma unroll
  for (int i = 0; i < 4; ++i) {
    int r = r0 + i * 8;  // n index
    dst[(size_t)(n0 + r) * 128 + k0 + c] = f2bf(tile[c][r]);
  }
}

// ---------------------------------------------------------------------------
// Uh f32 [128][512] -> packed f16-pair table UhH[k2][j] = (Uh[2k2][j],
// Uh[2k2+1][j]) as one uint. grid 128 x 256 (32768 entries).
// ---------------------------------------------------------------------------
__global__ __launch_bounds__(256) void uhconv_kernel(
    const float* __restrict__ Uh, unsigned int* __restrict__ UhH) {
  int idx = blockIdx.x * 256 + threadIdx.x;  // k2*512 + j
  int k2 = idx >> 9, j = idx & 511;
  float a = Uh[(size_t)(2 * k2) * 512 + j];
  float b = Uh[(size_t)(2 * k2 + 1) * 512 + j];
  union { _Float16 h[2]; unsigned int u; } p;
  p.h[0] = (_Float16)a;
  p.h[1] = (_Float16)b;
  UhH[idx] = p.u;
}

// ---------------------------------------------------------------------------
// x fp32 -> bf16, 8 elems/thread (round-2 exact). grid 1024 x 256
// ---------------------------------------------------------------------------
__global__ __launch_bounds__(256) void xconv_kernel(
    const float* __restrict__ x, unsigned short* __restrict__ xb) {
  int i = blockIdx.x * 256 + threadIdx.x;
  const float4* x4 = (const float4*)x;
  float4 a = x4[(size_t)i * 2], b = x4[(size_t)i * 2 + 1];
  ushort8v v;
  v[0] = f2bf(a.x); v[1] = f2bf(a.y); v[2] = f2bf(a.z); v[3] = f2bf(a.w);
  v[4] = f2bf(b.x); v[5] = f2bf(b.y); v[6] = f2bf(b.z); v[7] = f2bf(b.w);
  *(ushort8v*)(xb + (size_t)i * 8) = v;
}

// ---------------------------------------------------------------------------
// MFMA GEMM (round-2 exact, single A/B): C[M][N] = A[M][128]@BT[N][128]^T+bias
// Block tile 128x64, 256 thr = 4 waves. XOR-swizzle (row&7)<<4 on 16B chunks.
// ---------------------------------------------------------------------------
__global__ __launch_bounds__(256) void mfma_gemm_kernel(
    const unsigned short* __restrict__ A, const unsigned short* __restrict__ BTm,
    const float* __restrict__ bias, float* __restrict__ C, int N) {
  __shared__ unsigned short As[128 * 128];
  __shared__ unsigned short Bs[64 * 128];
  int tid = threadIdx.x;
  int m0 = blockIdx.x * 128, n0 = blockIdx.y * 64;
  #pragma unroll
  for (int i = 0; i < 8; ++i) {
    int cix = i * 256 + tid, row = cix >> 4, ch = cix & 15;
    ushort8v v = *(const ushort8v*)(A + (size_t)(m0 + row) * 128 + ch * 8);
    *(ushort8v*)&As[row * 128 + ((ch ^ (row & 7)) << 3)] = v;
  }
  #pragma unroll
  for (int i = 0; i < 4; ++i) {
    int cix = i * 256 + tid, row = cix >> 4, ch = cix & 15;
    ushort8v v = *(const ushort8v*)(BTm + (size_t)(n0 + row) * 128 + ch * 8);
    *(ushort8v*)&Bs[row * 128 + ((ch ^ (row & 7)) << 3)] = v;
  }
  __syncthreads();
  int lane = tid & 63, w = tid >> 6;
  int col = lane & 15, grp = lane >> 4;

  f32x4 acc[2][4];
  #pragma unroll
  for (int tm = 0; tm < 2; ++tm)
    #pragma unroll
    for (int tn = 0; tn < 4; ++tn) acc[tm][tn] = (f32x4){0.f, 0.f, 0.f, 0.f};

  #pragma unroll
  for (int kk = 0; kk < 4; ++kk) {
    int ch = kk * 4 + grp;
    short8v af[2], bf[4];
    #pragma unroll
    for (int tm = 0; tm < 2; ++tm) {
      int row = w * 32 + tm * 16 + col;
      af[tm] = *(const short8v*)&As[row * 128 + ((ch ^ (row & 7)) << 3)];
    }
    #pragma unroll
    for (int tn = 0; tn < 4; ++tn) {
      int row = tn * 16 + col;
      bf[tn] = *(const short8v*)&Bs[row * 128 + ((ch ^ (row & 7)) << 3)];
    }
    #pragma unroll
    for (int tm = 0; tm < 2; ++tm)
      #pragma unroll
      for (int tn = 0; tn < 4; ++tn)
        acc[tm][tn] = __builtin_amdgcn_mfma_f32_16x16x32_bf16(af[tm], bf[tn],
                                                              acc[tm][tn], 0, 0, 0);
  }

  #pragma unroll
  for (int tm = 0; tm < 2; ++tm)
    #pragma unroll
    for (int tn = 0; tn < 4; ++tn) {
      int cg = n0 + tn * 16 + col;
      float bv = bias[cg];
      int rbase = m0 + w * 32 + tm * 16 + grp * 4;
      #pragma unroll
      for (int r = 0; r < 4; ++r)
        C[(size_t)(rbase + r) * N + cg] = acc[tm][tn][r] + bv;
    }
}

// ---------------------------------------------------------------------------
// MFMA GEMM, 128x128 tile (final GEMM): C = A[M][128]@BT[N][128]^T + bias.
// 256 thr = 4 waves; wave owns a 64x64 quadrant (wr = (w>>1)*64, wc =
// (w&1)*64), acc[4][4]. Per kk: 8 fragment reads feed 16 MFMAs (2x the
// MFMA-per-LDS-read of the 128x64 tile) and staging barriers amortize 2x.
// Same swizzle/staging/epilogue pattern as the proven template.
// grid (M/128, N/128)
// ---------------------------------------------------------------------------
__global__ __launch_bounds__(256) void mfma_gemm128_kernel(
    const unsigned short* __restrict__ A, const unsigned short* __restrict__ BTm,
    const float* __restrict__ bias, float* __restrict__ C, int N) {
  __shared__ unsigned short As[128 * 128];
  __shared__ unsigned short Bs[128 * 128];
  int tid = threadIdx.x;
  int m0 = blockIdx.x * 128, n0 = blockIdx.y * 128;
  #pragma unroll
  for (int i = 0; i < 8; ++i) {
    int cix = i * 256 + tid, row = cix >> 4, ch = cix & 15;
    ushort8v v = *(const ushort8v*)(A + (size_t)(m0 + row) * 128 + ch * 8);
    *(ushort8v*)&As[row * 128 + ((ch ^ (row & 7)) << 3)] = v;
  }
  #pragma unroll
  for (int i = 0; i < 8; ++i) {
    int cix = i * 256 + tid, row = cix >> 4, ch = cix & 15;
    ushort8v v = *(const ushort8v*)(BTm + (size_t)(n0 + row) * 128 + ch * 8);
    *(ushort8v*)&Bs[row * 128 + ((ch ^ (row & 7)) << 3)] = v;
  }
  __syncthreads();
  int lane = tid & 63, w = tid >> 6;
  int wr = (w >> 1) * 64, wc = (w & 1) * 64;
  int col = lane & 15, grp = lane >> 4;

  f32x4 acc[4][4];
  #pragma unroll
  for (int tm = 0; tm < 4; ++tm)
    #pragma unroll
    for (int tn = 0; tn < 4; ++tn) acc[tm][tn] = (f32x4){0.f, 0.f, 0.f, 0.f};

  #pragma unroll
  for (int kk = 0; kk < 4; ++kk) {
    int ch = kk * 4 + grp;
    short8v af[4], bf[4];
    #pragma unroll
    for (int tm = 0; tm < 4; ++tm) {
      int row = wr + tm * 16 + col;
      af[tm] = *(const short8v*)&As[row * 128 + ((ch ^ (row & 7)) << 3)];
    }
    #pragma unroll
    for (int tn = 0; tn < 4; ++tn) {
      int row = wc + tn * 16 + col;
      bf[tn] = *(const short8v*)&Bs[row * 128 + ((ch ^ (row & 7)) << 3)];
    }
    #pragma unroll
    for (int tm = 0; tm < 4; ++tm)
      #pragma unroll
      for (int tn = 0; tn < 4; ++tn)
        acc[tm][tn] = __builtin_amdgcn_mfma_f32_16x16x32_bf16(af[tm], bf[tn],
                                                              acc[tm][tn], 0, 0, 0);
  }

  #pragma unroll
  for (int tm = 0; tm < 4; ++tm)
    #pragma unroll
    for (int tn = 0; tn < 4; ++tn) {
      int cg = n0 + wc + tn * 16 + col;
      float bv = bias[cg];
      int rbase = m0 + wr + tm * 16 + grp * 4;
      #pragma unroll
      for (int r = 0; r < 4; ++r)
        C[(size_t)(rbase + r) * N + cg] = acc[tm][tn][r] + bv;
    }
}

// ---------------------------------------------------------------------------
// Multi-mat MFMA GEMM (round-4 exact): C = sum_s A_s@BT_s^T + bias.
// ---------------------------------------------------------------------------
__global__ __launch_bounds__(256) void mfma_gemm3_kernel(
    const unsigned short* __restrict__ A0, const unsigned short* __restrict__ A1,
    const unsigned short* __restrict__ A2, const unsigned short* __restrict__ B0,
    const unsigned short* __restrict__ B1, const unsigned short* __restrict__ B2,
    int nmat, const float* __restrict__ bias, float* __restrict__ C, int N) {
  __shared__ unsigned short As[128 * 128];
  __shared__ unsigned short Bs[64 * 128];
  int tid = threadIdx.x;
  int m0 = blockIdx.x * 128, n0 = blockIdx.y * 64;
  int lane = tid & 63, w = tid >> 6;
  int col = lane & 15, grp = lane >> 4;

  f32x4 acc[2][4];
  #pragma unroll
  for (int tm = 0; tm < 2; ++tm)
    #pragma unroll
    for (int tn = 0; tn < 4; ++tn) acc[tm][tn] = (f32x4){0.f, 0.f, 0.f, 0.f};

  for (int s = 0; s < nmat; ++s) {
    const unsigned short* A   = (s == 0) ? A0 : (s == 1) ? A1 : A2;
    const unsigned short* BTm = (s == 0) ? B0 : (s == 1) ? B1 : B2;
    if (s) __syncthreads();
    #pragma unroll
    for (int i = 0; i < 8; ++i) {
      int cix = i * 256 + tid, row = cix >> 4, ch = cix & 15;
      ushort8v v = *(const ushort8v*)(A + (size_t)(m0 + row) * 128 + ch * 8);
      *(ushort8v*)&As[row * 128 + ((ch ^ (row & 7)) << 3)] = v;
    }
    #pragma unroll
    for (int i = 0; i < 4; ++i) {
      int cix = i * 256 + tid, row = cix >> 4, ch = cix & 15;
      ushort8v v = *(const ushort8v*)(BTm + (size_t)(n0 + row) * 128 + ch * 8);
      *(ushort8v*)&Bs[row * 128 + ((ch ^ (row & 7)) << 3)] = v;
    }
    __syncthreads();

    #pragma unroll
    for (int kk = 0; kk < 4; ++kk) {
      int ch = kk * 4 + grp;
      short8v af[2], bf[4];
      #pragma unroll
      for (int tm = 0; tm < 2; ++tm) {
        int row = w * 32 + tm * 16 + col;
        af[tm] = *(const short8v*)&As[row * 128 + ((ch ^ (row & 7)) << 3)];
      }
      #pragma unroll
      for (int tn = 0; tn < 4; ++tn) {
        int row = tn * 16 + col;
        bf[tn] = *(const short8v*)&Bs[row * 128 + ((ch ^ (row & 7)) << 3)];
      }
      #pragma unroll
      for (int tm = 0; tm < 2; ++tm)
        #pragma unroll
        for (int tn = 0; tn < 4; ++tn)
          acc[tm][tn] = __builtin_amdgcn_mfma_f32_16x16x32_bf16(
              af[tm], bf[tn], acc[tm][tn], 0, 0, 0);
    }
  }

  #pragma unroll
  for (int tm = 0; tm < 2; ++tm)
    #pragma unroll
    for (int tn = 0; tn < 4; ++tn) {
      int cg = n0 + tn * 16 + col;
      float bv = bias[cg];
      int rbase = m0 + w * 32 + tm * 16 + grp * 4;
      #pragma unroll
      for (int r = 0; r < 4; ++r)
        C[(size_t)(rbase + r) * N + cg] = acc[tm][tn][r] + bv;
    }
}

// ---------------------------------------------------------------------------
// GAT via MFMA, 2-deep ping-pong pipeline (round-8 exact, proven).
// grid (512, 2), 256 thr = 4 waves.
// ---------------------------------------------------------------------------
__global__ __launch_bounds__(256) void gat_mfma_kernel(
    const float* __restrict__ sneigh, const float* __restrict__ tneigh,
    const unsigned short* __restrict__ wcT, const float* __restrict__ qb,
    unsigned short* __restrict__ spb, unsigned short* __restrict__ tpb) {
  int g = blockIdx.y;
  const float* neigh = g ? tneigh : sneigh;
  const unsigned short* wc = wcT + g * 32768;
  unsigned short* outp = g ? tpb : spb;

  __shared__ unsigned short Bsh[256 * 128];  // 64 KB
  int tid = threadIdx.x;
  #pragma unroll
  for (int i = 0; i < 16; ++i) {
    int cix = i * 256 + tid, row = cix >> 4, ch = cix & 15;
    ushort8v v = *(const ushort8v*)(wc + row * 128 + ch * 8);
    *(ushort8v*)&Bsh[row * 128 + ((ch ^ (row & 7)) << 3)] = v;
  }
  __syncthreads();

  int lane = tid & 63, wid = tid >> 6;
  int col = lane & 15, grp = lane >> 4;

  const int NIT = 8;
  int btbase = blockIdx.x * (4 * NIT) + wid * NIT;

  float4 bufA[8], bufB[8];
  float qA[8], qB[8];

  auto load_bt = [&](int bt, float4 (&fa)[8], float (&qv)[8]) {
    const float* nb = neigh + ((size_t)bt * 16 + col) * 128 + grp * 8;
    #pragma unroll
    for (int kk = 0; kk < 4; ++kk) {
      fa[2 * kk]     = *(const float4*)(nb + kk * 32);
      fa[2 * kk + 1] = *(const float4*)(nb + kk * 32 + 4);
    }
    const float* qrow = qb + (size_t)bt * 256 + g * 128 + col;
    #pragma unroll
    for (int t = 0; t < 8; ++t) qv[t] = qrow[t * 16];
  };

  auto step = [&](int bt, int btn, float4 (&cur)[8], float (&qc)[8],
                  float4 (&nxt)[8], float (&qn)[8]) {
    load_bt(btn, nxt, qn);  // prefetch: no dependency with the work below

    short8v af[4];
    #pragma unroll
    for (int kk = 0; kk < 4; ++kk) {
      float4 a = cur[2 * kk], b = cur[2 * kk + 1];
      short8v t;
      t[0] = (short)f2bf(a.x); t[1] = (short)f2bf(a.y);
      t[2] = (short)f2bf(a.z); t[3] = (short)f2bf(a.w);
      t[4] = (short)f2bf(b.x); t[5] = (short)f2bf(b.y);
      t[6] = (short)f2bf(b.z); t[7] = (short)f2bf(b.w);
      af[kk] = t;
    }

    f32x4 acc[16];
    #pragma unroll
    for (int nt = 0; nt < 16; ++nt) acc[nt] = (f32x4){0.f, 0.f, 0.f, 0.f};

    #pragma unroll
    for (int kk = 0; kk < 4; ++kk) {
      int ch = kk * 4 + grp;
      #pragma unroll
      for (int nt = 0; nt < 16; ++nt) {
        int row = nt * 16 + col;
        short8v bfv = *(const short8v*)&Bsh[row * 128 + ((ch ^ (row & 7)) << 3)];
        acc[nt] = __builtin_amdgcn_mfma_f32_16x16x32_bf16(af[kk], bfv, acc[nt],
                                                          0, 0, 0);
      }
    }

    // softmax over n and weighted sum; d = 16*t + col
    #pragma unroll
    for (int t = 0; t < 8; ++t) {
      float qvv = qc[t];
      float e0 = qvv + acc[8 + t][0], e1 = qvv + acc[8 + t][1];
      float e2 = qvv + acc[8 + t][2], e3 = qvv + acc[8 + t][3];
      e0 = (e0 > 0.f) ? e0 : 0.2f * e0;
      e1 = (e1 > 0.f) ? e1 : 0.2f * e1;
      e2 = (e2 > 0.f) ? e2 : 0.2f * e2;
      e3 = (e3 > 0.f) ? e3 : 0.2f * e3;
      float mx = fmaxf(fmaxf(e0, e1), fmaxf(e2, e3));
      mx = fmaxf(mx, __shfl_xor(mx, 16));
      mx = fmaxf(mx, __shfl_xor(mx, 32));
      float p0 = __expf(e0 - mx), p1 = __expf(e1 - mx);
      float p2 = __expf(e2 - mx), p3 = __expf(e3 - mx);
      float s = p0 + p1 + p2 + p3;
      float o = p0 * acc[t][0] + p1 * acc[t][1] + p2 * acc[t][2] + p3 * acc[t][3];
      s += __shfl_xor(s, 16); s += __shfl_xor(s, 32);
      o += __shfl_xor(o, 16); o += __shfl_xor(o, 32);
      if (grp == (t & 3)) outp[(size_t)bt * 128 + t * 16 + col] = f2bf(o / s);
    }
  };

  load_bt(btbase, bufA, qA);
  #pragma unroll
  for (int p = 0; p < NIT / 2; ++p) {
    int bt = btbase + 2 * p;
    int b2 = (bt + 2 < BT) ? bt + 2 : bt;  // clamped, always-valid prefetch
    step(bt, bt + 1, bufA, qA, bufB, qB);
    step(bt + 1, b2, bufB, qB, bufA, qA);
  }
}

// ---------------------------------------------------------------------------
// LSTM scan v6 (round-11 exact, best measured): 512 thr, lb(512,2), f16-pair
// dot2 matvec; h f16 in LDS; Uh packed f16 pairs in 64 VGPRs.
// ---------------------------------------------------------------------------
__global__ __launch_bounds__(512, 2) void lstm_kernel(
    const float* __restrict__ pre, const unsigned int* __restrict__ UhH,
    unsigned short* __restrict__ hsb) {
  int b = blockIdx.x;
  int j = threadIdx.x;
  __shared__ _Float16 hh[128];
  __shared__ float nl_lds[512];
  unsigned int u2[64];
  #pragma unroll
  for (int k2 = 0; k2 < 64; ++k2) u2[k2] = UhH[k2 * 512 + j];
  float c = 0.f;
  if (j < 128) hh[j] = (_Float16)0.f;
  __syncthreads();
  const float4* hv4 = (const float4*)hh;  // 16 float4 = 128 f16
  const float* prow = pre + (size_t)b * 128 * 512 + j;
  unsigned short* hrow = hsb + (size_t)b * 128 * 128 + (j & 127);
  float pcur = prow[0];
  for (int t = 0; t < 128; ++t) {
    float pnext = (t < 127) ? prow[(size_t)(t + 1) * 512] : 0.f;

    // g = pcur + h @ Uh[:,j] via f16 dot2, 4 independent chains
    float ga = pcur, gb = 0.f, gc = 0.f, gd = 0.f;
    #pragma unroll
    for (int i = 0; i < 4; ++i) {
      float4 v0 = hv4[i * 4 + 0];
      float4 v1 = hv4[i * 4 + 1];
      float4 v2 = hv4[i * 4 + 2];
      float4 v3 = hv4[i * 4 + 3];
      int kb = i * 16;
      ga = dot2f(v0.x, u2[kb + 0], ga);
      gb = dot2f(v0.y, u2[kb + 1], gb);
      gc = dot2f(v0.z, u2[kb + 2], gc);
      gd = dot2f(v0.w, u2[kb + 3], gd);
      ga = dot2f(v1.x, u2[kb + 4], ga);
      gb = dot2f(v1.y, u2[kb + 5], gb);
      gc = dot2f(v1.z, u2[kb + 6], gc);
      gd = dot2f(v1.w, u2[kb + 7], gd);
      ga = dot2f(v2.x, u2[kb + 8], ga);
      gb = dot2f(v2.y, u2[kb + 9], gb);
      gc = dot2f(v2.z, u2[kb + 10], gc);
      gd = dot2f(v2.w, u2[kb + 11], gd);
      ga = dot2f(v3.x, u2[kb + 12], ga);
      gb = dot2f(v3.y, u2[kb + 13], gb);
      gc = dot2f(v3.z, u2[kb + 14], gc);
      gd = dot2f(v3.w, u2[kb + 15], gd);
    }
    float g = (ga + gb) + (gc + gd);

    // nonlinearity on ALL threads (wave-uniform branch: j<384 <=> wave<6)
    float nl = (j < 384) ? fsig(g) : ftanh(g);
    nl_lds[j] = nl;
    __syncthreads();  // partials ready; hh reads of this step done

    if (j < 128) {
      float ig = nl_lds[j], fg = nl_lds[j + 128];
      float og = nl_lds[j + 256], cg = nl_lds[j + 384];
      c = fg * c + ig * cg;
      float h = ftanh(og * c);
      hh[j] = (_Float16)h;
      hrow[(size_t)t * 128] = f2bf(h);
    }
    __syncthreads();
    pcur = pnext;
  }
}

// ---------------------------------------------------------------------------
extern "C" void kernel_launch(void* const* d_in, const int* in_sizes, int n_in,
                              void* d_out, int out_size, void* d_ws,
                              size_t ws_size, hipStream_t stream) {
  const float* x    = (const float*)d_in[0];
  const float* sn   = (const float*)d_in[1];
  const float* tn   = (const float*)d_in[2];
  const float* s_w  = (const float*)d_in[3];
  const float* s_ak = (const float*)d_in[4];
  const float* s_ab = (const float*)d_in[5];
  const float* t_w  = (const float*)d_in[6];
  const float* t_ak = (const float*)d_in[7];
  const float* t_ab = (const float*)d_in[8];
  const float* Wx   = (const float*)d_in[9];
  const float* Uh   = (const float*)d_in[10];
  const float* Ub   = (const float*)d_in[11];
  const float* sW   = (const float*)d_in[12];
  const float* tW   = (const float*)d_in[13];
  const float* Wf   = (const float*)d_in[14];
  const float* bfb  = (const float*)d_in[15];
  float* out = (float*)d_out;

  // ws layout — byte-identical to rounds 2/4/5/6/8/11 (proven to fit):
  unsigned short* wqT = (unsigned short*)d_ws;                      // 65536 B
  unsigned short* wcT = (unsigned short*)((char*)d_ws + 65536);     // 131072 B
  unsigned short* WfT = (unsigned short*)((char*)d_ws + 196608);    // 1048576 B
  unsigned short* hsb = (unsigned short*)((char*)d_ws + 1245184);   // 4194304 B
  float*          abp = (float*)((char*)d_ws + 5439488);            // 1024 B

  // d_out scratch — byte-identical to round 11:
  float* pre = out;                                        // [0, 8388608)
  float* q   = out + 12582912;                             // [16384][256]
  unsigned short* xb  = (unsigned short*)(out + 16777216); // [16384][128] bf16
  unsigned short* spb = (unsigned short*)(out + 17825792); // [16384][128] bf16
  unsigned short* tpb = (unsigned short*)(out + 18874368); // [16384][128] bf16
  unsigned short* WxT = (unsigned short*)(out + 19922944); // [512][128] bf16
  unsigned short* sWT = (unsigned short*)(out + 19955712); // [512][128] bf16
  unsigned short* tWT = (unsigned short*)(out + 19988480); // [512][128] bf16
  unsigned int*   UhH = (unsigned int*)(out + 20054016);   // [64][512] uint

  prep_dots_kernel<<<dim3(128, 4), 128, 0, stream>>>(s_w, s_ak, s_ab, t_w, t_ak,
                                                     t_ab, wqT, wcT, abp);
  prep_wfT_kernel<<<dim3(128, 4), 256, 0, stream>>>(Wf, WfT);
  tconv_kernel<<<dim3(16, 4, 3), 256, 0, stream>>>(Wx, sW, tW, WxT, sWT, tWT,
                                                   512);
  uhconv_kernel<<<128, 256, 0, stream>>>(Uh, UhH);
  xconv_kernel<<<1024, 256, 0, stream>>>(x, xb);
  mfma_gemm_kernel<<<dim3(128, 4), 256, 0, stream>>>(xb, wqT, abp, q, 256);
  gat_mfma_kernel<<<dim3(512, 2), 256, 0, stream>>>(sn, tn, wcT, q, spb, tpb);
  mfma_gemm3_kernel<<<dim3(128, 8), 256, 0, stream>>>(xb, spb, tpb, WxT, sWT,
                                                      tWT, 3, Ub, pre, 512);
  lstm_kernel<<<128, 512, 0, stream>>>(pre, UhH, hsb);
  mfma_gemm128_kernel<<<dim3(128, 32), 256, 0, stream>>>(hsb, WfT, bfb, out,
                                                         CC);
}